// Round 21
// baseline (2922.316 us; speedup 1.0000x reference)
//
#include <hip/hip_runtime.h>
#include <hip/hip_bf16.h>

using short8  = __attribute__((ext_vector_type(8))) short;
using f32x4   = __attribute__((ext_vector_type(4))) float;
using uint32x4 = __attribute__((ext_vector_type(4))) unsigned;

static constexpr int N_NODES = 100000;
static constexpr int N_EDGES = 3200000;
static constexpr int IN_DIM  = 512;
static constexpr int OUT_DIM = 128;
static constexpr int NBINS   = (N_NODES + 255) / 256;  // 391 bins of 256 nodes
static constexpr int NB      = 1024;                   // binning blocks
static constexpr int CHUNK   = N_EDGES / NB;           // 3125 edges/block (exact)
static constexpr int EPB     = (CHUNK + 255) / 256;    // 13 edges/thread
static constexpr int SLACK   = 9216;                   // bin capacity (8186+6sigma)
static constexpr int RSH     = 13;                     // source-range shift (2MB slices)
static constexpr int NRANGE  = (N_NODES + (1 << RSH) - 1) >> RSH;  // 13

__device__ __forceinline__ short f2bf(float f) {
  unsigned u = __builtin_bit_cast(unsigned, f);
  u = (u + 0x7FFFu + ((u >> 16) & 1u)) >> 16;  // RNE
  return (short)u;
}

__device__ __forceinline__ void gload16(const void* g, void* l) {
  __builtin_amdgcn_global_load_lds(
      (const __attribute__((address_space(1))) unsigned int*)g,
      (__attribute__((address_space(3))) unsigned int*)l, 16, 0, 0);
}

// ------- W [512][128] f32 -> WT [128][512] bf16; also init bin cursors ----
__global__ __launch_bounds__(256) void cast_WT(const float* __restrict__ W,
                                               short* __restrict__ WT,
                                               int* __restrict__ cursor) {
  const int idx = blockIdx.x * 256 + threadIdx.x;  // 65536 total
  if (idx < NBINS) cursor[idx] = idx * SLACK;
  const int c = idx >> 9, k = idx & 511;
  WT[(size_t)c * 512 + k] = f2bf(W[(size_t)k * 128 + c]);
}

// ------------- m97-style LDS GEMM: xwb = (x@W)*dinv, bf16 out -------------
__global__ __launch_bounds__(256) void gemm_lds(const float* __restrict__ x,
                                                const short* __restrict__ WT,
                                                const float* __restrict__ dinv,
                                                unsigned short* __restrict__ xwb) {
  __shared__ float          Abuf[2][128 * 32];  // 2 x 16KB
  __shared__ unsigned short Bbuf[2][128 * 32];  // 2 x 8KB
  const int tid = threadIdx.x;
  const int w   = tid >> 6;
  const int l   = tid & 63;
  const int wr  = w >> 1, wc = w & 1;
  const int lr  = l & 15;
  const int lk  = l >> 4;
  const int row0 = blockIdx.x * 128;
  const char* xb  = reinterpret_cast<const char*>(x);
  const char* wtb = reinterpret_cast<const char*>(WT);
  const int wbase = (tid & ~63) * 16;  // wave-uniform LDS chunk base (bytes)

  auto stage = [&](int kb, int buf) {
#pragma unroll
    for (int t = 0; t < 4; ++t) {
      const int f = t * 256 + tid;  // unit index 0..1023
      const int r = f >> 3;
      const int u = f & 7;
      const int grow = min(row0 + r, N_NODES - 1);
      const char* src = xb + (size_t)grow * 2048 + kb * 128 + ((u ^ (r & 7)) << 4);
      gload16(src, (char*)Abuf[buf] + t * 4096 + wbase);
    }
#pragma unroll
    for (int t = 0; t < 2; ++t) {
      const int f = t * 256 + tid;  // unit index 0..511
      const int c = f >> 2;
      const int u = f & 3;
      const char* src = wtb + (size_t)c * 1024 + kb * 64 + ((u ^ (c & 3)) << 4);
      gload16(src, (char*)Bbuf[buf] + t * 4096 + wbase);
    }
  };

  auto cvt2 = [](float lo, float hi) -> unsigned {
    __hip_bfloat162 h = __float22bfloat162_rn(make_float2(lo, hi));
    unsigned r;
    __builtin_memcpy(&r, &h, 4);
    return r;
  };

  f32x4 acc[4][4] = {};

  auto compute = [&](int buf) {
    const char* Ab = (const char*)Abuf[buf];
    const char* Bb = (const char*)Bbuf[buf];
    short8 a[4], b[4];
#pragma unroll
    for (int rf = 0; rf < 4; ++rf) {
      const int rl = wr * 64 + rf * 16 + lr;
      const char* base = Ab + rl * 128;
      const f32x4 r0 = *(const f32x4*)(base + (((2 * lk)     ^ (rl & 7)) << 4));
      const f32x4 r1 = *(const f32x4*)(base + (((2 * lk + 1) ^ (rl & 7)) << 4));
      uint32x4 ua;
      ua[0] = cvt2(r0[0], r0[1]);
      ua[1] = cvt2(r0[2], r0[3]);
      ua[2] = cvt2(r1[0], r1[1]);
      ua[3] = cvt2(r1[2], r1[3]);
      a[rf] = __builtin_bit_cast(short8, ua);
    }
#pragma unroll
    for (int cf = 0; cf < 4; ++cf) {
      const int cl = wc * 64 + cf * 16 + lr;
      b[cf] = *(const short8*)(Bb + cl * 64 + ((lk ^ (cl & 3)) << 4));
    }
#pragma unroll
    for (int rf = 0; rf < 4; ++rf)
#pragma unroll
      for (int cf = 0; cf < 4; ++cf)
        acc[rf][cf] = __builtin_amdgcn_mfma_f32_16x16x32_bf16(a[rf], b[cf], acc[rf][cf], 0, 0, 0);
  };

  stage(0, 0);
  __syncthreads();
  for (int kb = 0; kb < 16; ++kb) {
    if (kb < 15) stage(kb + 1, (kb + 1) & 1);
    compute(kb & 1);
    __syncthreads();
  }

#pragma unroll
  for (int rf = 0; rf < 4; ++rf) {
#pragma unroll
    for (int j = 0; j < 4; ++j) {
      const int row = row0 + wr * 64 + rf * 16 + lk * 4 + j;
      if (row < N_NODES) {
        const float sc = dinv[row];  // prescale: xwb = xw * dinv[row]
        unsigned short* o = &xwb[(size_t)row * OUT_DIM + wc * 64 + lr];
#pragma unroll
        for (int cf = 0; cf < 4; ++cf)
          o[cf * 16] = (unsigned short)f2bf(acc[rf][cf][j] * sc);
      }
    }
  }
}

// ==== fused binning: LDS histogram + bulk atomic reserve + scatter ========
__global__ __launch_bounds__(256) void bin_scatter(const int* __restrict__ erow,
                                                   const int* __restrict__ ecol,
                                                   int* __restrict__ cursor,
                                                   unsigned* __restrict__ benc) {
  __shared__ int hist[NBINS];
  __shared__ int cur[NBINS];
  const int blk = blockIdx.x, tid = threadIdx.x;
  const int e0 = blk * CHUNK;
  for (int i = tid; i < NBINS; i += 256) hist[i] = 0;
  __syncthreads();

  int cc[EPB], rr[EPB];
#pragma unroll
  for (int i = 0; i < EPB; ++i) {
    const int e = e0 + tid + i * 256;
    const bool ok = (tid + i * 256) < CHUNK;
    cc[i] = ok ? ecol[e] : -1;
    rr[i] = ok ? erow[e] : 0;
    if (ok) atomicAdd(&hist[cc[i] >> 8], 1);
  }
  __syncthreads();
  for (int i = tid; i < NBINS; i += 256)
    cur[i] = hist[i] ? atomicAdd(&cursor[i], hist[i]) : 0;
  __syncthreads();
#pragma unroll
  for (int i = 0; i < EPB; ++i) {
    if (cc[i] >= 0) {
      const unsigned enc = (unsigned)rr[i] | ((unsigned)(cc[i] & 255) << 24);
      const int p = atomicAdd(&cur[cc[i] >> 8], 1);
      benc[p] = enc;
    }
  }
}

// B: per-bin degrees -> dinv, and 13-range counting sort by SOURCE range.
__global__ __launch_bounds__(256) void bin_build_push(const unsigned* __restrict__ benc,
                                                      const int* __restrict__ cursor,
                                                      unsigned* __restrict__ bsorted,
                                                      float* __restrict__ dinv) {
  __shared__ int deg[256];
  __shared__ int rcnt[NRANGE];
  __shared__ int rbase[NRANGE];
  const int b = blockIdx.x, tid = threadIdx.x;
  const int e0 = b * SLACK, e1 = cursor[b];
  deg[tid] = 0;
  if (tid < NRANGE) rcnt[tid] = 0;
  __syncthreads();
  for (int e = e0 + tid; e < e1; e += 256) {
    const unsigned v = benc[e];
    atomicAdd(&deg[v >> 24], 1);
    atomicAdd(&rcnt[(v & 0x00FFFFFFu) >> RSH], 1);
  }
  __syncthreads();
  const int node = (b << 8) + tid;
  if (node < N_NODES) dinv[node] = rsqrtf((float)deg[tid] + 1.0f);
  if (tid == 0) {
    int run = 0;
#pragma unroll
    for (int r = 0; r < NRANGE; ++r) { rbase[r] = run; run += rcnt[r]; }
  }
  __syncthreads();
  for (int e = e0 + tid; e < e1; e += 256) {
    const unsigned v = benc[e];
    const int p = atomicAdd(&rbase[(v & 0x00FFFFFFu) >> RSH], 1);
    bsorted[e0 + p] = v;
  }
}

// ------- gather: PUSH into LDS accumulators, src-sorted edge stream -------
// Block = bin (256 dests). acc[256][64] f32 (64KB, col ^ (row&60) swizzle).
// Two col-half passes. 4 waves walk the bin's edges interleaved (stride-4
// 64-edge batches); all blocks sweep src ranges in sync -> L2-resident reads.
__global__ __launch_bounds__(256) void gather_push(const unsigned short* __restrict__ xwb,
                                                   const float* __restrict__ dinv,
                                                   const int* __restrict__ cursor,
                                                   const unsigned* __restrict__ bsorted,
                                                   const float* __restrict__ bias,
                                                   float* __restrict__ out) {
  __shared__ float acc[256][64];  // 64KB
  const int b    = blockIdx.x;
  const int tid  = threadIdx.x;
  const int w    = tid >> 6;
  const int lane = tid & 63;
  const int sl   = lane & 31;
  const int hb   = lane >> 5;
  const unsigned* xwb32 = reinterpret_cast<const unsigned*>(xwb);
  const int e0 = b * SLACK;
  const int e1 = cursor[b];
  const int nbatch = (e1 - e0 + 63) >> 6;
  const int node = (b << 8) + tid;
  const int swz_me = tid & 60;

  for (int half = 0; half < 2; ++half) {
    // init: self-loop row-half (prescaled by dinv[node]) or zeros
    if (node < N_NODES) {
      const unsigned* xr = xwb32 + (size_t)node * 64 + half * 32;
#pragma unroll
      for (int q = 0; q < 32; ++q) {
        const unsigned v = xr[q];
        acc[tid][(2 * q)     ^ swz_me] = __builtin_bit_cast(float, v << 16);
        acc[tid][(2 * q + 1) ^ swz_me] = __builtin_bit_cast(float, v & 0xFFFF0000u);
      }
    } else {
#pragma unroll
      for (int q = 0; q < 64; ++q) acc[tid][q] = 0.f;
    }
    __syncthreads();

    for (int j = w; j < nbatch; j += 4) {
      const int myE = e0 + j * 64 + lane;
      const unsigned enc = (myE < e1) ? bsorted[myE] : 0xFFFFFFFFu;
#pragma unroll
      for (int s = 0; s < 32; ++s) {
        const unsigned el = __shfl(enc, 2 * s);
        const unsigned eh = __shfl(enc, 2 * s + 1);
        const unsigned mine = hb ? eh : el;
        const int src = (int)(mine & 0x00FFFFFFu);
        if (src < N_NODES) {
          const unsigned v = xwb32[(size_t)src * 64 + half * 32 + sl];
          const int ld = (int)(mine >> 24);
          const int sz = ld & 60;
          atomicAdd(&acc[ld][(2 * sl)     ^ sz], __builtin_bit_cast(float, v << 16));
          atomicAdd(&acc[ld][(2 * sl + 1) ^ sz], __builtin_bit_cast(float, v & 0xFFFF0000u));
        }
      }
    }
    __syncthreads();

    // writeout: out = acc * dinv[node] + bias
    if (node < N_NODES) {
      const float di = dinv[node];
      float* orow = &out[(size_t)node * OUT_DIM + half * 64];
#pragma unroll
      for (int q4 = 0; q4 < 16; ++q4) {
        float4 o;
        o.x = acc[tid][(q4 * 4 + 0) ^ swz_me] * di + bias[half * 64 + q4 * 4 + 0];
        o.y = acc[tid][(q4 * 4 + 1) ^ swz_me] * di + bias[half * 64 + q4 * 4 + 1];
        o.z = acc[tid][(q4 * 4 + 2) ^ swz_me] * di + bias[half * 64 + q4 * 4 + 2];
        o.w = acc[tid][(q4 * 4 + 3) ^ swz_me] * di + bias[half * 64 + q4 * 4 + 3];
        *reinterpret_cast<float4*>(&orow[q4 * 4]) = o;
      }
    }
    __syncthreads();
  }
}

extern "C" void kernel_launch(void* const* d_in, const int* in_sizes, int n_in,
                              void* d_out, int out_size, void* d_ws, size_t ws_size,
                              hipStream_t stream) {
  const float* x    = (const float*)d_in[0];
  const int*   eidx = (const int*)d_in[1];
  const float* W    = (const float*)d_in[2];
  const float* b    = (const float*)d_in[3];
  float* out = (float*)d_out;

  const int* erow = eidx;            // sources
  const int* ecol = eidx + N_EDGES;  // destinations

  char* ws = (char*)d_ws;
  size_t off = 0;
  auto alloc = [&](size_t bytes) -> void* {
    void* p = ws + off;
    off = (off + bytes + 255) & ~(size_t)255;
    return p;
  };
  unsigned short* xwb = (unsigned short*)alloc((size_t)N_NODES * OUT_DIM * sizeof(short)); // 25.6MB
  short* WT        = (short*)alloc((size_t)OUT_DIM * IN_DIM * sizeof(short));    // 128KB
  float* dinv      = (float*)alloc((size_t)N_NODES * sizeof(float));             // 400KB
  int*   cursor    = (int*)alloc((size_t)NBINS * sizeof(int));
  unsigned* benc    = (unsigned*)alloc((size_t)NBINS * SLACK * sizeof(unsigned)); // 14.4MB
  unsigned* bsorted = (unsigned*)alloc((size_t)NBINS * SLACK * sizeof(unsigned)); // 14.4MB

  cast_WT<<<256, 256, 0, stream>>>(W, WT, cursor);
  bin_scatter<<<NB, 256, 0, stream>>>(erow, ecol, cursor, benc);
  bin_build_push<<<NBINS, 256, 0, stream>>>(benc, cursor, bsorted, dinv);
  gemm_lds<<<(N_NODES + 127) / 128, 256, 0, stream>>>(x, WT, dinv, xwb);
  gather_push<<<NBINS, 256, 0, stream>>>(xwb, dinv, cursor, bsorted, b, out);
}

// Round 22
// 262.688 us; speedup vs baseline: 11.1247x; 11.1247x over previous
//
#include <hip/hip_runtime.h>
#include <hip/hip_bf16.h>

using short8  = __attribute__((ext_vector_type(8))) short;
using f32x4   = __attribute__((ext_vector_type(4))) float;
using uint32x4 = __attribute__((ext_vector_type(4))) unsigned;

static constexpr int N_NODES = 100000;
static constexpr int N_EDGES = 3200000;
static constexpr int IN_DIM  = 512;
static constexpr int OUT_DIM = 128;
static constexpr int NBINS   = (N_NODES + 255) / 256;  // 391 bins of 256 nodes
static constexpr int NB      = 1024;                   // binning blocks
static constexpr int CHUNK   = N_EDGES / NB;           // 3125 edges/block (exact)
static constexpr int EPB     = (CHUNK + 255) / 256;    // 13 edges/thread
static constexpr int SLACK   = 9216;                   // bin capacity (8186+6sigma)
static constexpr int RSH     = 13;                     // source-range shift
static constexpr int NRANGE  = (N_NODES + (1 << RSH) - 1) >> RSH;  // 13

__device__ __forceinline__ short f2bf(float f) {
  unsigned u = __builtin_bit_cast(unsigned, f);
  u = (u + 0x7FFFu + ((u >> 16) & 1u)) >> 16;  // RNE
  return (short)u;
}

__device__ __forceinline__ void gload16(const void* g, void* l) {
  __builtin_amdgcn_global_load_lds(
      (const __attribute__((address_space(1))) unsigned int*)g,
      (__attribute__((address_space(3))) unsigned int*)l, 16, 0, 0);
}

// ------- W [512][128] f32 -> WT [128][512] bf16; also init bin cursors ----
__global__ __launch_bounds__(256) void cast_WT(const float* __restrict__ W,
                                               short* __restrict__ WT,
                                               int* __restrict__ cursor) {
  const int idx = blockIdx.x * 256 + threadIdx.x;  // 65536 total
  if (idx < NBINS) cursor[idx] = idx * SLACK;
  const int c = idx >> 9, k = idx & 511;
  WT[(size_t)c * 512 + k] = f2bf(W[(size_t)k * 128 + c]);
}

// ------------- m97-style LDS GEMM: xwb = (x@W)*dinv, bf16 out -------------
__global__ __launch_bounds__(256) void gemm_lds(const float* __restrict__ x,
                                                const short* __restrict__ WT,
                                                const float* __restrict__ dinv,
                                                unsigned short* __restrict__ xwb) {
  __shared__ float          Abuf[2][128 * 32];  // 2 x 16KB
  __shared__ unsigned short Bbuf[2][128 * 32];  // 2 x 8KB
  const int tid = threadIdx.x;
  const int w   = tid >> 6;
  const int l   = tid & 63;
  const int wr  = w >> 1, wc = w & 1;
  const int lr  = l & 15;
  const int lk  = l >> 4;
  const int row0 = blockIdx.x * 128;
  const char* xb  = reinterpret_cast<const char*>(x);
  const char* wtb = reinterpret_cast<const char*>(WT);
  const int wbase = (tid & ~63) * 16;  // wave-uniform LDS chunk base (bytes)

  auto stage = [&](int kb, int buf) {
#pragma unroll
    for (int t = 0; t < 4; ++t) {
      const int f = t * 256 + tid;  // unit index 0..1023
      const int r = f >> 3;
      const int u = f & 7;
      const int grow = min(row0 + r, N_NODES - 1);
      const char* src = xb + (size_t)grow * 2048 + kb * 128 + ((u ^ (r & 7)) << 4);
      gload16(src, (char*)Abuf[buf] + t * 4096 + wbase);
    }
#pragma unroll
    for (int t = 0; t < 2; ++t) {
      const int f = t * 256 + tid;  // unit index 0..511
      const int c = f >> 2;
      const int u = f & 3;
      const char* src = wtb + (size_t)c * 1024 + kb * 64 + ((u ^ (c & 3)) << 4);
      gload16(src, (char*)Bbuf[buf] + t * 4096 + wbase);
    }
  };

  auto cvt2 = [](float lo, float hi) -> unsigned {
    __hip_bfloat162 h = __float22bfloat162_rn(make_float2(lo, hi));
    unsigned r;
    __builtin_memcpy(&r, &h, 4);
    return r;
  };

  f32x4 acc[4][4] = {};

  auto compute = [&](int buf) {
    const char* Ab = (const char*)Abuf[buf];
    const char* Bb = (const char*)Bbuf[buf];
    short8 a[4], b[4];
#pragma unroll
    for (int rf = 0; rf < 4; ++rf) {
      const int rl = wr * 64 + rf * 16 + lr;
      const char* base = Ab + rl * 128;
      const f32x4 r0 = *(const f32x4*)(base + (((2 * lk)     ^ (rl & 7)) << 4));
      const f32x4 r1 = *(const f32x4*)(base + (((2 * lk + 1) ^ (rl & 7)) << 4));
      uint32x4 ua;
      ua[0] = cvt2(r0[0], r0[1]);
      ua[1] = cvt2(r0[2], r0[3]);
      ua[2] = cvt2(r1[0], r1[1]);
      ua[3] = cvt2(r1[2], r1[3]);
      a[rf] = __builtin_bit_cast(short8, ua);
    }
#pragma unroll
    for (int cf = 0; cf < 4; ++cf) {
      const int cl = wc * 64 + cf * 16 + lr;
      b[cf] = *(const short8*)(Bb + cl * 64 + ((lk ^ (cl & 3)) << 4));
    }
#pragma unroll
    for (int rf = 0; rf < 4; ++rf)
#pragma unroll
      for (int cf = 0; cf < 4; ++cf)
        acc[rf][cf] = __builtin_amdgcn_mfma_f32_16x16x32_bf16(a[rf], b[cf], acc[rf][cf], 0, 0, 0);
  };

  stage(0, 0);
  __syncthreads();
  for (int kb = 0; kb < 16; ++kb) {
    if (kb < 15) stage(kb + 1, (kb + 1) & 1);
    compute(kb & 1);
    __syncthreads();
  }

#pragma unroll
  for (int rf = 0; rf < 4; ++rf) {
#pragma unroll
    for (int j = 0; j < 4; ++j) {
      const int row = row0 + wr * 64 + rf * 16 + lk * 4 + j;
      if (row < N_NODES) {
        const float sc = dinv[row];  // prescale: xwb = xw * dinv[row]
        unsigned short* o = &xwb[(size_t)row * OUT_DIM + wc * 64 + lr];
#pragma unroll
        for (int cf = 0; cf < 4; ++cf)
          o[cf * 16] = (unsigned short)f2bf(acc[rf][cf][j] * sc);
      }
    }
  }
}

// ==== fused binning: LDS histogram + bulk atomic reserve + scatter ========
__global__ __launch_bounds__(256) void bin_scatter(const int* __restrict__ erow,
                                                   const int* __restrict__ ecol,
                                                   int* __restrict__ cursor,
                                                   unsigned* __restrict__ benc) {
  __shared__ int hist[NBINS];
  __shared__ int cur[NBINS];
  const int blk = blockIdx.x, tid = threadIdx.x;
  const int e0 = blk * CHUNK;
  for (int i = tid; i < NBINS; i += 256) hist[i] = 0;
  __syncthreads();

  int cc[EPB], rr[EPB];
#pragma unroll
  for (int i = 0; i < EPB; ++i) {
    const int e = e0 + tid + i * 256;
    const bool ok = (tid + i * 256) < CHUNK;
    cc[i] = ok ? ecol[e] : -1;
    rr[i] = ok ? erow[e] : 0;
    if (ok) atomicAdd(&hist[cc[i] >> 8], 1);
  }
  __syncthreads();
  for (int i = tid; i < NBINS; i += 256)
    cur[i] = hist[i] ? atomicAdd(&cursor[i], hist[i]) : 0;
  __syncthreads();
#pragma unroll
  for (int i = 0; i < EPB; ++i) {
    if (cc[i] >= 0) {
      const unsigned enc = (unsigned)rr[i] | ((unsigned)(cc[i] & 255) << 24);
      const int p = atomicAdd(&cur[cc[i] >> 8], 1);
      benc[p] = enc;
    }
  }
}

// B: per-bin CSR build (padded segments) with per-dest source-range sub-sort.
__global__ __launch_bounds__(256) void bin_build(const unsigned* __restrict__ benc,
                                                 const int* __restrict__ cursor,
                                                 int* __restrict__ brow,
                                                 int* __restrict__ offs,
                                                 int* __restrict__ oend,
                                                 float* __restrict__ dinv) {
  __shared__ int hist[256 * NRANGE];  // 13KB: count -> cursor (in place)
  __shared__ int sh[256];
  const int b = blockIdx.x, tid = threadIdx.x;
  const int e0 = b * SLACK;
  const int e1 = cursor[b];  // e0 + count_b
  for (int i = tid; i < 256 * NRANGE; i += 256) hist[i] = 0;
  __syncthreads();
  for (int e = e0 + tid; e < e1; e += 256) {
    const unsigned v = benc[e];
    const int key = (int)(v >> 24) * NRANGE + (int)((v & 0x00FFFFFFu) >> RSH);
    atomicAdd(&hist[key], 1);
  }
  __syncthreads();
  // per-dest serial exclusive prefix over its NRANGE counters; total = degree
  const int base = tid * NRANGE;
  int d0 = 0;
#pragma unroll
  for (int r = 0; r < NRANGE; ++r) {
    const int c = hist[base + r];
    hist[base + r] = d0;
    d0 += c;
  }
  sh[tid] = d0;
  __syncthreads();
  for (int d = 1; d < 256; d <<= 1) {
    const int tv = (tid >= d) ? sh[tid - d] : 0;
    __syncthreads();
    sh[tid] += tv;
    __syncthreads();
  }
  const int myoff = e0 + sh[tid] - d0;  // padded CSR offset for node (b<<8)+tid
#pragma unroll
  for (int r = 0; r < NRANGE; ++r) hist[base + r] += myoff;  // -> cursors
  const int node = (b << 8) + tid;
  if (node < N_NODES) {
    offs[node] = myoff;
    oend[node] = myoff + d0;
    dinv[node] = rsqrtf((float)d0 + 1.0f);
  }
  __syncthreads();
  for (int e = e0 + tid; e < e1; e += 256) {
    const unsigned v = benc[e];
    const int src = (int)(v & 0x00FFFFFFu);
    const int key = (int)(v >> 24) * NRANGE + (src >> RSH);
    const int p = atomicAdd(&hist[key], 1);
    brow[p] = src;
  }
}

// ------- gather: one wave per node, 16-deep in-flight gathers -------------
__global__ __launch_bounds__(256) void gather_out(const unsigned short* __restrict__ xwb,
                                                  const float* __restrict__ dinv,
                                                  const int* __restrict__ offs,
                                                  const int* __restrict__ oend,
                                                  const int* __restrict__ brow,
                                                  const float* __restrict__ bias,
                                                  float* __restrict__ out) {
  const int lane = threadIdx.x & 63;
  const int node = blockIdx.x * (blockDim.x >> 6) + (threadIdx.x >> 6);
  if (node >= N_NODES) return;
  const float di = dinv[node];
  const int c0 = lane * 2;

  auto ld2 = [&](int r) -> float2 {
    const unsigned v = *reinterpret_cast<const unsigned*>(&xwb[(size_t)r * OUT_DIM + c0]);
    float2 f;
    f.x = __builtin_bit_cast(float, v << 16);
    f.y = __builtin_bit_cast(float, v & 0xFFFF0000u);
    return f;
  };

  float2 acc = ld2(node);  // self-loop (prescaled)
  float2 acc2 = make_float2(0.f, 0.f);

  int e = offs[node];
  const int e1 = oend[node];
  for (; e + 16 <= e1; e += 16) {
    int r[16];
#pragma unroll
    for (int i = 0; i < 16; ++i) r[i] = brow[e + i];
    float2 v[16];
#pragma unroll
    for (int i = 0; i < 16; ++i) v[i] = ld2(r[i]);
#pragma unroll
    for (int i = 0; i < 16; i += 2) {
      acc.x += v[i].x + v[i + 1].x;
      acc.y += v[i].y + v[i + 1].y;
    }
  }
  for (; e + 4 <= e1; e += 4) {
    const int r0 = brow[e], r1 = brow[e + 1], r2 = brow[e + 2], r3 = brow[e + 3];
    const float2 v0 = ld2(r0), v1 = ld2(r1), v2 = ld2(r2), v3 = ld2(r3);
    acc2.x += (v0.x + v1.x) + (v2.x + v3.x);
    acc2.y += (v0.y + v1.y) + (v2.y + v3.y);
  }
  for (; e < e1; ++e) {
    const float2 v = ld2(brow[e]);
    acc2.x += v.x;
    acc2.y += v.y;
  }
  acc.x += acc2.x;
  acc.y += acc2.y;

  const float2 bb = *reinterpret_cast<const float2*>(&bias[c0]);
  float2 o;
  o.x = acc.x * di + bb.x;
  o.y = acc.y * di + bb.y;
  *reinterpret_cast<float2*>(&out[(size_t)node * OUT_DIM + c0]) = o;
}

extern "C" void kernel_launch(void* const* d_in, const int* in_sizes, int n_in,
                              void* d_out, int out_size, void* d_ws, size_t ws_size,
                              hipStream_t stream) {
  const float* x    = (const float*)d_in[0];
  const int*   eidx = (const int*)d_in[1];
  const float* W    = (const float*)d_in[2];
  const float* b    = (const float*)d_in[3];
  float* out = (float*)d_out;

  const int* erow = eidx;            // sources
  const int* ecol = eidx + N_EDGES;  // destinations

  char* ws = (char*)d_ws;
  size_t off = 0;
  auto alloc = [&](size_t bytes) -> void* {
    void* p = ws + off;
    off = (off + bytes + 255) & ~(size_t)255;
    return p;
  };
  unsigned short* xwb = (unsigned short*)alloc((size_t)N_NODES * OUT_DIM * sizeof(short)); // 25.6MB
  short* WT      = (short*)alloc((size_t)OUT_DIM * IN_DIM * sizeof(short));    // 128KB
  float* dinv    = (float*)alloc((size_t)N_NODES * sizeof(float));             // 400KB
  int*   offs    = (int*)alloc((size_t)N_NODES * sizeof(int));                 // 400KB
  int*   oend    = (int*)alloc((size_t)N_NODES * sizeof(int));                 // 400KB
  int*   cursor  = (int*)alloc((size_t)NBINS * sizeof(int));
  int*   brow    = (int*)alloc((size_t)NBINS * SLACK * sizeof(int));           // 14.4MB
  unsigned* benc = (unsigned*)alloc((size_t)NBINS * SLACK * sizeof(unsigned)); // 14.4MB

  cast_WT<<<256, 256, 0, stream>>>(W, WT, cursor);
  bin_scatter<<<NB, 256, 0, stream>>>(erow, ecol, cursor, benc);
  bin_build<<<NBINS, 256, 0, stream>>>(benc, cursor, brow, offs, oend, dinv);
  gemm_lds<<<(N_NODES + 127) / 128, 256, 0, stream>>>(x, WT, dinv, xwb);
  gather_out<<<(N_NODES + 3) / 4, 256, 0, stream>>>(xwb, dinv, offs, oend, brow, b, out);
}